// Round 8
// baseline (190.643 us; speedup 1.0000x reference)
//
#include <hip/hip_runtime.h>

// Tricubic B-spline eval, p=3, NC=64/axis, DOUT=3, knots t[i]=clamp((i-3)/61,0,1).
// R8 = R5 structure (best known) + eval processes 2 points per thread
// interleaved (2x MLP on ds_read chains), scatter at CHUNK_S=1024 for
// occupancy, overflow handling merged into eval's grid.
// Scatter stays LDS-staged with coalesced segment writes (R2/R6 showed any
// random-order per-point global store/atomic pass costs >=60 us).

#define NC 64
#define NSEG 61
#define NCELLS 512
#define WDIM 11
#define CAP 2560      // mean cell count 1953, sd 44
#define CHUNK 512     // eval queries per block
#define NCHUNK 5      // 5*512 == CAP
#define CHUNK_S 1024  // scatter queries per block
#define OVF_CAP 4096

typedef float vfloat4 __attribute__((ext_vector_type(4)));

__device__ __forceinline__ float rcpf(float x) {
#if __has_builtin(__builtin_amdgcn_rcpf)
  return __builtin_amdgcn_rcpf(x);
#else
  return 1.0f / x;
#endif
}

__device__ __forceinline__ int span_of(float x) {
  float xc = fminf(fmaxf(x, 0.0f), 1.0f);
  int j = (int)floorf(xc * (float)NSEG);
  return j > NSEG - 1 ? NSEG - 1 : (j < 0 ? 0 : j);
}

__device__ __forceinline__ float knotv(int i) {
  float v = (float)(i - 3) * (1.0f / (float)NSEG);
  return fminf(fmaxf(v, 0.0f), 1.0f);
}

// Cox-de Boor (A2.2): span j (k=j+3), 4 nonzero basis values for idx j..j+3.
__device__ __forceinline__ void basis4(float x, int j, float N[4]) {
  float xc = fminf(fmaxf(x, 0.0f), 1.0f);
  int k = j + 3;
  float left[4], right[4];
  N[0] = 1.0f;
#pragma unroll
  for (int jj = 1; jj <= 3; ++jj) {
    left[jj] = xc - knotv(k + 1 - jj);
    right[jj] = knotv(k + jj) - xc;
    float saved = 0.0f;
#pragma unroll
    for (int r = 0; r < jj; ++r) {
      float temp = N[r] * rcpf(right[r + 1] + left[jj - r]);
      N[r] = saved + right[r + 1] * temp;
      saved = left[jj - r] * temp;
    }
    N[jj] = saved;
  }
}

__device__ __forceinline__ void eval_point(float x, float y, float z, int jx,
                                           int jy, int jz,
                                           const float* __restrict__ cp,
                                           float o[3]) {
  float Nx[4], Ny[4], Nz[4];
  basis4(x, jx, Nx);
  basis4(y, jy, Ny);
  basis4(z, jz, Nz);
  float ax = 0, ay = 0, az = 0;
#pragma unroll 1
  for (int c = 0; c < 4; ++c) {
#pragma unroll
    for (int b = 0; b < 4; ++b) {
      float w = Ny[b] * Nz[c];
      const float* row = cp + 3 * (size_t)(jx + NC * (jy + b + NC * (jz + c)));
      vfloat4 f0, f1, f2;
      __builtin_memcpy(&f0, row + 0, 16);
      __builtin_memcpy(&f1, row + 4, 16);
      __builtin_memcpy(&f2, row + 8, 16);
      ax += w * (Nx[0] * f0.x + Nx[1] * f0.w + Nx[2] * f1.z + Nx[3] * f2.y);
      ay += w * (Nx[0] * f0.y + Nx[1] * f1.x + Nx[2] * f1.w + Nx[3] * f2.z);
      az += w * (Nx[0] * f0.z + Nx[1] * f1.y + Nx[2] * f2.x + Nx[3] * f2.w);
    }
  }
  o[0] = ax; o[1] = ay; o[2] = az;
}

// Exclusive scan of arr[512] with 256 threads. All threads must call.
__device__ __forceinline__ void scan512_t256(int* arr) {
  int tid = threadIdx.x;
  int c0 = arr[tid], c1 = arr[tid + 256];
#pragma unroll
  for (int off = 1; off < 512; off <<= 1) {
    int t0 = (tid >= off) ? arr[tid - off] : 0;
    int t1 = ((tid + 256) >= off) ? arr[tid + 256 - off] : 0;
    __syncthreads();
    arr[tid] += t0;
    arr[tid + 256] += t1;
    __syncthreads();
  }
  arr[tid] -= c0;
  arr[tid + 256] -= c1;
  __syncthreads();
}

// ---------------- scatter: LDS-staged, cell-ordered coalesced writes --------
__global__ __launch_bounds__(256) void scatter_capped(
    const float* __restrict__ q, int* __restrict__ gcursor,
    int* __restrict__ ovfcnt, float4* __restrict__ ovf,
    float4* __restrict__ sorted, int nq) {
  __shared__ int hist[NCELLS];   // counts -> (after scan) local excl base
  __shared__ int gb[NCELLS];     // global segment base per cell
  __shared__ int lcur[NCELLS];   // local rank cursors
  __shared__ float4 stage[CHUNK_S];
  __shared__ int addr[CHUNK_S];
  int b = blockIdx.x, tid = threadIdx.x;
  for (int c = tid; c < NCELLS; c += 256) { hist[c] = 0; lcur[c] = 0; }
  __syncthreads();

  int s = b * CHUNK_S, e = min(nq, s + CHUNK_S);
  int nblk = e - s;
  float xs[4], ys[4], zs[4];
  int cells[4];
  unsigned us[4];
#pragma unroll
  for (int it = 0; it < 4; ++it) {
    int i = s + it * 256 + tid;
    cells[it] = -1;
    if (i < e) {
      float xyz[3];
      __builtin_memcpy(xyz, q + 3 * (size_t)i, 12);
      xs[it] = xyz[0]; ys[it] = xyz[1]; zs[it] = xyz[2];
      int jx = span_of(xyz[0]), jy = span_of(xyz[1]), jz = span_of(xyz[2]);
      cells[it] = (jx >> 3) + 8 * (jy >> 3) + 64 * (jz >> 3);
      us[it] = (unsigned)i | ((unsigned)(jx & 7) << 20) |
               ((unsigned)(jy & 7) << 23) | ((unsigned)(jz & 7) << 26);
      atomicAdd(&hist[cells[it]], 1);
    }
  }
  __syncthreads();
  // claim one global segment per nonempty cell (2 returning atomics/thread)
  int n0 = hist[tid], n1 = hist[tid + 256];
  gb[tid] = n0 ? atomicAdd(&gcursor[tid], n0) : 0;
  gb[tid + 256] = n1 ? atomicAdd(&gcursor[tid + 256], n1) : 0;
  __syncthreads();
  scan512_t256(hist);  // hist[c] = local exclusive base
#pragma unroll
  for (int it = 0; it < 4; ++it) {
    int cell = cells[it];
    if (cell < 0) continue;
    int rank = atomicAdd(&lcur[cell], 1);
    int rloc = hist[cell] + rank;
    int rg = gb[cell] + rank;
    if (rg < CAP) {
      stage[rloc] = make_float4(xs[it], ys[it], zs[it],
                                __int_as_float((int)us[it]));
      addr[rloc] = cell * CAP + rg;
    } else {
      addr[rloc] = -1;
      int p = atomicAdd(ovfcnt, 1);
      if (p < OVF_CAP)
        ovf[p] = make_float4(xs[it], ys[it], zs[it],
                             __int_as_float((int)(us[it] & 0xFFFFFu)));
    }
  }
  __syncthreads();
  // drain: consecutive lanes -> consecutive addresses within cell segments
  for (int j = tid; j < nblk; j += 256) {
    int a = addr[j];
    if (a >= 0) sorted[a] = stage[j];
  }
}

// ---------------- eval: LDS window + in-chunk sort + dual-point MLP ---------
__global__ __launch_bounds__(256) void eval_kernel(
    const float4* __restrict__ sorted, const int* __restrict__ cellcnt,
    const int* __restrict__ ovfcnt, const float4* __restrict__ ovf,
    const float* __restrict__ cp, float* __restrict__ out) {
  int tid = threadIdx.x;
  if (blockIdx.x >= NCELLS * NCHUNK) {  // overflow block (block-uniform)
    int n = min(*ovfcnt, OVF_CAP);
    for (int i = tid; i < n; i += 256) {
      float4 s = ovf[i];
      int oi = __float_as_int(s.w);
      float o[3];
      eval_point(s.x, s.y, s.z, span_of(s.x), span_of(s.y), span_of(s.z), cp, o);
      __builtin_memcpy(out + 3 * (size_t)oi, o, 12);
    }
    return;
  }
  int cid = blockIdx.x / NCHUNK;
  int chunkid = blockIdx.x % NCHUNK;
  int cnt = min(cellcnt[cid], CAP);
  int q0 = chunkid * CHUNK;
  if (q0 >= cnt) return;  // block-uniform: safe before barriers
  int n = min(cnt - q0, CHUNK);
  size_t base = (size_t)cid * CAP + q0;
  int ox = (cid & 7) * 8, oy = ((cid >> 3) & 7) * 8, oz = (cid >> 6) * 8;

  __shared__ float4 win[WDIM * WDIM * WDIM];  // 21296 B
  __shared__ int bins[CHUNK];                 // 2048 B
  __shared__ unsigned short order[CHUNK];     // 1024 B
  for (int e2 = tid; e2 < WDIM * WDIM * WDIM; e2 += 256) {
    int lx = e2 % WDIM, t = e2 / WDIM;
    int ly = t % WDIM, lz = t / WDIM;
    int gx = min(ox + lx, NC - 1), gy = min(oy + ly, NC - 1),
        gz = min(oz + lz, NC - 1);
    const float* p = cp + 3 * (size_t)(gx + NC * (gy + NC * gz));
    win[e2] = make_float4(p[0], p[1], p[2], 0.0f);
  }
  bins[tid] = 0;
  bins[tid + 256] = 0;
  // counting-sort the chunk by 9-bit subspan key
  int k0 = -1, k1 = -1, r0 = 0, r1 = 0;
  if (tid < n)
    k0 = (int)(((unsigned)__float_as_int(sorted[base + tid].w) >> 20) & 511u);
  if (tid + 256 < n)
    k1 = (int)(((unsigned)__float_as_int(sorted[base + tid + 256].w) >> 20) & 511u);
  __syncthreads();
  if (k0 >= 0) r0 = atomicAdd(&bins[k0], 1);
  if (k1 >= 0) r1 = atomicAdd(&bins[k1], 1);
  __syncthreads();
  scan512_t256(bins);
  if (k0 >= 0) order[bins[k0] + r0] = (unsigned short)tid;
  if (k1 >= 0) order[bins[k1] + r1] = (unsigned short)(tid + 256);
  __syncthreads();

  // dual-point interleaved eval: thread owns sorted-ranks tid and tid+256
  bool vA = tid < n, vB = tid + 256 < n;
  int iA = vA ? order[tid] : 0, iB = vB ? order[tid + 256] : 0;
  float4 sA = sorted[base + iA];
  float4 sB = sorted[base + iB];
  unsigned uA = (unsigned)__float_as_int(sA.w);
  unsigned uB = (unsigned)__float_as_int(sB.w);
  int oiA = (int)(uA & 0xFFFFFu), oiB = (int)(uB & 0xFFFFFu);
  int lxA = (int)((uA >> 20) & 7), lyA = (int)((uA >> 23) & 7),
      lzA = (int)((uA >> 26) & 7);
  int lxB = (int)((uB >> 20) & 7), lyB = (int)((uB >> 23) & 7),
      lzB = (int)((uB >> 26) & 7);
  float NxA[4], NyA[4], NzA[4], NxB[4], NyB[4], NzB[4];
  basis4(sA.x, ox + lxA, NxA);
  basis4(sA.y, oy + lyA, NyA);
  basis4(sA.z, oz + lzA, NzA);
  basis4(sB.x, ox + lxB, NxB);
  basis4(sB.y, oy + lyB, NyB);
  basis4(sB.z, oz + lzB, NzB);

  float axA = 0, ayA = 0, azA = 0, axB = 0, ayB = 0, azB = 0;
#pragma unroll
  for (int c = 0; c < 4; ++c) {
#pragma unroll
    for (int b = 0; b < 4; ++b) {
      const float4* rowA = &win[((lzA + c) * WDIM + (lyA + b)) * WDIM + lxA];
      const float4* rowB = &win[((lzB + c) * WDIM + (lyB + b)) * WDIM + lxB];
      float4 a0 = rowA[0], a1 = rowA[1], a2 = rowA[2], a3 = rowA[3];
      float4 b0 = rowB[0], b1 = rowB[1], b2 = rowB[2], b3 = rowB[3];
      float wA = NyA[b] * NzA[c], wB = NyB[b] * NzB[c];
      axA += wA * (NxA[0] * a0.x + NxA[1] * a1.x + NxA[2] * a2.x + NxA[3] * a3.x);
      ayA += wA * (NxA[0] * a0.y + NxA[1] * a1.y + NxA[2] * a2.y + NxA[3] * a3.y);
      azA += wA * (NxA[0] * a0.z + NxA[1] * a1.z + NxA[2] * a2.z + NxA[3] * a3.z);
      axB += wB * (NxB[0] * b0.x + NxB[1] * b1.x + NxB[2] * b2.x + NxB[3] * b3.x);
      ayB += wB * (NxB[0] * b0.y + NxB[1] * b1.y + NxB[2] * b2.y + NxB[3] * b3.y);
      azB += wB * (NxB[0] * b0.z + NxB[1] * b1.z + NxB[2] * b2.z + NxB[3] * b3.z);
    }
  }
  if (vA) {
    float o[3] = {axA, ayA, azA};
    __builtin_memcpy(out + 3 * (size_t)oiA, o, 12);
  }
  if (vB) {
    float o[3] = {axB, ayB, azB};
    __builtin_memcpy(out + 3 * (size_t)oiB, o, 12);
  }
}

// ---------------- fallback: direct ----------------
__global__ __launch_bounds__(256) void spline_direct_kernel(
    const float* __restrict__ q, const float* __restrict__ cp,
    float* __restrict__ out, int nq) {
  int i = blockIdx.x * 256 + threadIdx.x;
  if (i >= nq) return;
  float xyz[3];
  __builtin_memcpy(xyz, q + 3 * (size_t)i, 12);
  float o[3];
  eval_point(xyz[0], xyz[1], xyz[2], span_of(xyz[0]), span_of(xyz[1]),
             span_of(xyz[2]), cp, o);
  __builtin_memcpy(out + 3 * (size_t)i, o, 12);
}

extern "C" void kernel_launch(void* const* d_in, const int* in_sizes, int n_in,
                              void* d_out, int out_size, void* d_ws,
                              size_t ws_size, hipStream_t stream) {
  const float* queries = (const float*)d_in[0];
  const float* control = (const float*)d_in[1];
  float* out = (float*)d_out;
  int nq = in_sizes[0] / 3;

  // ws: gcursor[512] | ovfcnt | pad16 | ovf[OVF_CAP] f4 | sorted[512*CAP] f4
  size_t meta = (NCELLS + 1) * sizeof(int);
  size_t metap = (meta + 15) & ~15ull;
  size_t need = metap + (size_t)OVF_CAP * 16 + (size_t)NCELLS * CAP * 16;

  if (nq <= (1 << 20) && ws_size >= need) {
    int* gcursor = (int*)d_ws;
    int* ovfcnt = gcursor + NCELLS;
    float4* ovf = (float4*)((char*)d_ws + metap);
    float4* sorted = ovf + OVF_CAP;
    hipMemsetAsync(d_ws, 0, meta, stream);
    int nb = (nq + CHUNK_S - 1) / CHUNK_S;
    scatter_capped<<<nb, 256, 0, stream>>>(queries, gcursor, ovfcnt, ovf,
                                           sorted, nq);
    eval_kernel<<<NCELLS * NCHUNK + 1, 256, 0, stream>>>(sorted, gcursor,
                                                         ovfcnt, ovf, control,
                                                         out);
  } else {
    spline_direct_kernel<<<(nq + 255) / 256, 256, 0, stream>>>(queries, control,
                                                               out, nq);
  }
}

// Round 9
// 138.246 us; speedup vs baseline: 1.3790x; 1.3790x over previous
//
#include <hip/hip_runtime.h>

// Tricubic B-spline eval, p=3, NC=64/axis, DOUT=3, knots t[i]=clamp((i-3)/61,0,1).
// R9 = R5 structure + eval chunks of 1024 sorted by 6-bit (ly,lz) key via
// barrier-free wave scan (conflicts depend only on the row set, not lx).
// Single-point eval loop kept verbatim from R5 (56 VGPR — R8 showed dual-point
// unroll blows to 224 VGPR and 10% occupancy). Scatter = R5's LDS-staged
// coalesced-segment form (R2/R6: any random-order per-point global
// store/atomic pass costs >=60 us). Overflow merged into eval's grid.

#define NC 64
#define NSEG 61
#define NCELLS 512
#define WDIM 11
#define CAP 2560      // mean cell count 1953, sd 44
#define ECHUNK 1024   // eval queries per block
#define NCHUNK 3      // 3*1024 >= CAP
#define CHUNK_S 2048  // scatter queries per block
#define OVF_CAP 4096

typedef float vfloat4 __attribute__((ext_vector_type(4)));

__device__ __forceinline__ float rcpf(float x) {
#if __has_builtin(__builtin_amdgcn_rcpf)
  return __builtin_amdgcn_rcpf(x);
#else
  return 1.0f / x;
#endif
}

__device__ __forceinline__ int span_of(float x) {
  float xc = fminf(fmaxf(x, 0.0f), 1.0f);
  int j = (int)floorf(xc * (float)NSEG);
  return j > NSEG - 1 ? NSEG - 1 : (j < 0 ? 0 : j);
}

__device__ __forceinline__ float knotv(int i) {
  float v = (float)(i - 3) * (1.0f / (float)NSEG);
  return fminf(fmaxf(v, 0.0f), 1.0f);
}

// Cox-de Boor (A2.2): span j (k=j+3), 4 nonzero basis values for idx j..j+3.
__device__ __forceinline__ void basis4(float x, int j, float N[4]) {
  float xc = fminf(fmaxf(x, 0.0f), 1.0f);
  int k = j + 3;
  float left[4], right[4];
  N[0] = 1.0f;
#pragma unroll
  for (int jj = 1; jj <= 3; ++jj) {
    left[jj] = xc - knotv(k + 1 - jj);
    right[jj] = knotv(k + jj) - xc;
    float saved = 0.0f;
#pragma unroll
    for (int r = 0; r < jj; ++r) {
      float temp = N[r] * rcpf(right[r + 1] + left[jj - r]);
      N[r] = saved + right[r + 1] * temp;
      saved = left[jj - r] * temp;
    }
    N[jj] = saved;
  }
}

__device__ __forceinline__ void eval_point(float x, float y, float z, int jx,
                                           int jy, int jz,
                                           const float* __restrict__ cp,
                                           float o[3]) {
  float Nx[4], Ny[4], Nz[4];
  basis4(x, jx, Nx);
  basis4(y, jy, Ny);
  basis4(z, jz, Nz);
  float ax = 0, ay = 0, az = 0;
#pragma unroll 1
  for (int c = 0; c < 4; ++c) {
#pragma unroll
    for (int b = 0; b < 4; ++b) {
      float w = Ny[b] * Nz[c];
      const float* row = cp + 3 * (size_t)(jx + NC * (jy + b + NC * (jz + c)));
      vfloat4 f0, f1, f2;
      __builtin_memcpy(&f0, row + 0, 16);
      __builtin_memcpy(&f1, row + 4, 16);
      __builtin_memcpy(&f2, row + 8, 16);
      ax += w * (Nx[0] * f0.x + Nx[1] * f0.w + Nx[2] * f1.z + Nx[3] * f2.y);
      ay += w * (Nx[0] * f0.y + Nx[1] * f1.x + Nx[2] * f1.w + Nx[3] * f2.z);
      az += w * (Nx[0] * f0.z + Nx[1] * f1.y + Nx[2] * f2.x + Nx[3] * f2.w);
    }
  }
  o[0] = ax; o[1] = ay; o[2] = az;
}

// Exclusive scan of arr[512] with 256 threads. All threads must call.
__device__ __forceinline__ void scan512_t256(int* arr) {
  int tid = threadIdx.x;
  int c0 = arr[tid], c1 = arr[tid + 256];
#pragma unroll
  for (int off = 1; off < 512; off <<= 1) {
    int t0 = (tid >= off) ? arr[tid - off] : 0;
    int t1 = ((tid + 256) >= off) ? arr[tid + 256 - off] : 0;
    __syncthreads();
    arr[tid] += t0;
    arr[tid + 256] += t1;
    __syncthreads();
  }
  arr[tid] -= c0;
  arr[tid + 256] -= c1;
  __syncthreads();
}

// ---------------- scatter: LDS-staged, cell-ordered coalesced writes --------
__global__ __launch_bounds__(256) void scatter_capped(
    const float* __restrict__ q, int* __restrict__ gcursor,
    int* __restrict__ ovfcnt, float4* __restrict__ ovf,
    float4* __restrict__ sorted, int nq) {
  __shared__ int hist[NCELLS];   // counts -> (after scan) local excl base
  __shared__ int gb[NCELLS];     // global segment base per cell
  __shared__ int lcur[NCELLS];   // local rank cursors
  __shared__ float4 stage[CHUNK_S];
  __shared__ int addr[CHUNK_S];
  int b = blockIdx.x, tid = threadIdx.x;
  for (int c = tid; c < NCELLS; c += 256) { hist[c] = 0; lcur[c] = 0; }
  __syncthreads();

  int s = b * CHUNK_S, e = min(nq, s + CHUNK_S);
  int nblk = e - s;
  float xs[8], ys[8], zs[8];
  int cells[8];
  unsigned us[8];
#pragma unroll
  for (int it = 0; it < 8; ++it) {
    int i = s + it * 256 + tid;
    cells[it] = -1;
    if (i < e) {
      float xyz[3];
      __builtin_memcpy(xyz, q + 3 * (size_t)i, 12);
      xs[it] = xyz[0]; ys[it] = xyz[1]; zs[it] = xyz[2];
      int jx = span_of(xyz[0]), jy = span_of(xyz[1]), jz = span_of(xyz[2]);
      cells[it] = (jx >> 3) + 8 * (jy >> 3) + 64 * (jz >> 3);
      us[it] = (unsigned)i | ((unsigned)(jx & 7) << 20) |
               ((unsigned)(jy & 7) << 23) | ((unsigned)(jz & 7) << 26);
      atomicAdd(&hist[cells[it]], 1);
    }
  }
  __syncthreads();
  // claim one global segment per nonempty cell (2 returning atomics/thread)
  int n0 = hist[tid], n1 = hist[tid + 256];
  gb[tid] = n0 ? atomicAdd(&gcursor[tid], n0) : 0;
  gb[tid + 256] = n1 ? atomicAdd(&gcursor[tid + 256], n1) : 0;
  __syncthreads();
  scan512_t256(hist);  // hist[c] = local exclusive base
#pragma unroll
  for (int it = 0; it < 8; ++it) {
    int cell = cells[it];
    if (cell < 0) continue;
    int rank = atomicAdd(&lcur[cell], 1);
    int rloc = hist[cell] + rank;
    int rg = gb[cell] + rank;
    if (rg < CAP) {
      stage[rloc] = make_float4(xs[it], ys[it], zs[it],
                                __int_as_float((int)us[it]));
      addr[rloc] = cell * CAP + rg;
    } else {
      addr[rloc] = -1;
      int p = atomicAdd(ovfcnt, 1);
      if (p < OVF_CAP)
        ovf[p] = make_float4(xs[it], ys[it], zs[it],
                             __int_as_float((int)(us[it] & 0xFFFFFu)));
    }
  }
  __syncthreads();
  // drain: consecutive lanes -> consecutive addresses within cell segments
  for (int j = tid; j < nblk; j += 256) {
    int a = addr[j];
    if (a >= 0) sorted[a] = stage[j];
  }
}

// ---------------- eval: LDS window + (ly,lz) sort + single-point loop -------
__global__ __launch_bounds__(256) void eval_kernel(
    const float4* __restrict__ sorted, const int* __restrict__ cellcnt,
    const int* __restrict__ ovfcnt, const float4* __restrict__ ovf,
    const float* __restrict__ cp, float* __restrict__ out) {
  int tid = threadIdx.x;
  if (blockIdx.x >= NCELLS * NCHUNK) {  // overflow block (block-uniform)
    int n = min(*ovfcnt, OVF_CAP);
    for (int i = tid; i < n; i += 256) {
      float4 s = ovf[i];
      int oi = __float_as_int(s.w);
      float o[3];
      eval_point(s.x, s.y, s.z, span_of(s.x), span_of(s.y), span_of(s.z), cp, o);
      __builtin_memcpy(out + 3 * (size_t)oi, o, 12);
    }
    return;
  }
  int cid = blockIdx.x / NCHUNK;
  int chunkid = blockIdx.x % NCHUNK;
  int cnt = min(cellcnt[cid], CAP);
  int q0 = chunkid * ECHUNK;
  if (q0 >= cnt) return;  // block-uniform: safe before barriers
  int n = min(cnt - q0, ECHUNK);
  size_t base = (size_t)cid * CAP + q0;
  int ox = (cid & 7) * 8, oy = ((cid >> 3) & 7) * 8, oz = (cid >> 6) * 8;

  __shared__ float4 win[WDIM * WDIM * WDIM];   // 21296 B
  __shared__ int bins[64];                     // 256 B
  __shared__ unsigned short order[ECHUNK];     // 2048 B -> 23600 B total
  for (int e2 = tid; e2 < WDIM * WDIM * WDIM; e2 += 256) {
    int lx = e2 % WDIM, t = e2 / WDIM;
    int ly = t % WDIM, lz = t / WDIM;
    int gx = min(ox + lx, NC - 1), gy = min(oy + ly, NC - 1),
        gz = min(oz + lz, NC - 1);
    const float* p = cp + 3 * (size_t)(gx + NC * (gy + NC * gz));
    win[e2] = make_float4(p[0], p[1], p[2], 0.0f);
  }
  if (tid < 64) bins[tid] = 0;
  // load keys for my up-to-4 slots: key = ly + 8*lz (6 bits) — the row set,
  // which is all that matters for bank behavior (lx only shifts within a row)
  int key[4], rk[4];
#pragma unroll
  for (int it = 0; it < 4; ++it) {
    int idx = it * 256 + tid;
    key[it] = -1;
    if (idx < n)
      key[it] =
          (int)(((unsigned)__float_as_int(sorted[base + idx].w) >> 23) & 63u);
  }
  __syncthreads();
#pragma unroll
  for (int it = 0; it < 4; ++it)
    if (key[it] >= 0) rk[it] = atomicAdd(&bins[key[it]], 1);
  __syncthreads();
  if (tid < 64) {  // wave 0: barrier-free exclusive scan of 64 bins
    int v = bins[tid], incl = v;
#pragma unroll
    for (int off = 1; off < 64; off <<= 1) {
      int t = __shfl_up(incl, off, 64);
      if (tid >= off) incl += t;
    }
    bins[tid] = incl - v;
  }
  __syncthreads();
#pragma unroll
  for (int it = 0; it < 4; ++it)
    if (key[it] >= 0)
      order[bins[key[it]] + rk[it]] = (unsigned short)(it * 256 + tid);
  __syncthreads();

  // single-point eval loop (R5-proven register footprint)
  for (int t2 = tid; t2 < n; t2 += 256) {
    int lidx = order[t2];
    float4 s = sorted[base + lidx];  // L1-resident (16 KB window, just read)
    unsigned u = (unsigned)__float_as_int(s.w);
    int oi = (int)(u & 0xFFFFFu);
    int lx0 = (int)((u >> 20) & 7), ly0 = (int)((u >> 23) & 7),
        lz0 = (int)((u >> 26) & 7);
    float Nx[4], Ny[4], Nz[4];
    basis4(s.x, ox + lx0, Nx);
    basis4(s.y, oy + ly0, Ny);
    basis4(s.z, oz + lz0, Nz);

    float ax = 0.0f, ay = 0.0f, az = 0.0f;
#pragma unroll
    for (int c = 0; c < 4; ++c) {
#pragma unroll
      for (int b = 0; b < 4; ++b) {
        float w = Ny[b] * Nz[c];
        const float4* row = &win[((lz0 + c) * WDIM + (ly0 + b)) * WDIM + lx0];
        float4 p0 = row[0], p1 = row[1], p2 = row[2], p3 = row[3];
        ax += w * (Nx[0] * p0.x + Nx[1] * p1.x + Nx[2] * p2.x + Nx[3] * p3.x);
        ay += w * (Nx[0] * p0.y + Nx[1] * p1.y + Nx[2] * p2.y + Nx[3] * p3.y);
        az += w * (Nx[0] * p0.z + Nx[1] * p1.z + Nx[2] * p2.z + Nx[3] * p3.z);
      }
    }
    float o[3] = {ax, ay, az};
    __builtin_memcpy(out + 3 * (size_t)oi, o, 12);
  }
}

// ---------------- fallback: direct ----------------
__global__ __launch_bounds__(256) void spline_direct_kernel(
    const float* __restrict__ q, const float* __restrict__ cp,
    float* __restrict__ out, int nq) {
  int i = blockIdx.x * 256 + threadIdx.x;
  if (i >= nq) return;
  float xyz[3];
  __builtin_memcpy(xyz, q + 3 * (size_t)i, 12);
  float o[3];
  eval_point(xyz[0], xyz[1], xyz[2], span_of(xyz[0]), span_of(xyz[1]),
             span_of(xyz[2]), cp, o);
  __builtin_memcpy(out + 3 * (size_t)i, o, 12);
}

extern "C" void kernel_launch(void* const* d_in, const int* in_sizes, int n_in,
                              void* d_out, int out_size, void* d_ws,
                              size_t ws_size, hipStream_t stream) {
  const float* queries = (const float*)d_in[0];
  const float* control = (const float*)d_in[1];
  float* out = (float*)d_out;
  int nq = in_sizes[0] / 3;

  // ws: gcursor[512] | ovfcnt | pad16 | ovf[OVF_CAP] f4 | sorted[512*CAP] f4
  size_t meta = (NCELLS + 1) * sizeof(int);
  size_t metap = (meta + 15) & ~15ull;
  size_t need = metap + (size_t)OVF_CAP * 16 + (size_t)NCELLS * CAP * 16;

  if (nq <= (1 << 20) && ws_size >= need) {
    int* gcursor = (int*)d_ws;
    int* ovfcnt = gcursor + NCELLS;
    float4* ovf = (float4*)((char*)d_ws + metap);
    float4* sorted = ovf + OVF_CAP;
    hipMemsetAsync(d_ws, 0, meta, stream);
    int nb = (nq + CHUNK_S - 1) / CHUNK_S;
    scatter_capped<<<nb, 256, 0, stream>>>(queries, gcursor, ovfcnt, ovf,
                                           sorted, nq);
    eval_kernel<<<NCELLS * NCHUNK + 1, 256, 0, stream>>>(sorted, gcursor,
                                                         ovfcnt, ovf, control,
                                                         out);
  } else {
    spline_direct_kernel<<<(nq + 255) / 256, 256, 0, stream>>>(queries, control,
                                                               out, nq);
  }
}